// Round 1
// baseline (133.736 us; speedup 1.0000x reference)
//
#include <hip/hip_runtime.h>

// DSSIM loss: 1 - mean(SSIM(x,y)), 11x11 gaussian window (sigma=1.5), zero-pad.
// Separable conv: horizontal blur of {x, y, x^2, y^2, xy} into LDS, then
// vertical blur + per-pixel ssim + block reduction.

#define TILE   32
#define PAD    5
#define IN_T   (TILE + 2*PAD)   // 42
#define IMG_W  512
#define IMG_H  512
#define NPIX   12582912         // 16*3*512*512
#define NBLK   12288            // 48 planes * 16*16 tiles

__global__ __launch_bounds__(256)
void dssim_main(const float* __restrict__ x, const float* __restrict__ y,
                float* __restrict__ partial) {
    __shared__ float sx[IN_T][IN_T];
    __shared__ float sy[IN_T][IN_T];
    __shared__ float hbuf[5][IN_T][TILE];
    __shared__ float wsum[4];

    const int t = threadIdx.x;
    const int tx0 = blockIdx.x * TILE;
    const int ty0 = blockIdx.y * TILE;
    const size_t pbase = (size_t)blockIdx.z * (IMG_W * IMG_H);

    // gaussian weights (normalized), computed per-thread; matches np ref
    float g[11];
    {
        float s = 0.f;
#pragma unroll
        for (int i = 0; i < 11; ++i) {
            float d = (float)(i - 5);
            g[i] = expf(-(d * d) * (1.0f / 4.5f));   // 2*sigma^2 = 4.5
            s += g[i];
        }
        float inv = 1.0f / s;
#pragma unroll
        for (int i = 0; i < 11; ++i) g[i] *= inv;
    }

    // ---- load input tile with halo (zero padding outside image) ----
    for (int idx = t; idx < IN_T * IN_T; idx += 256) {
        int r = idx / IN_T, c = idx % IN_T;
        int gy = ty0 + r - PAD, gx = tx0 + c - PAD;
        float xv = 0.f, yv = 0.f;
        if (gy >= 0 && gy < IMG_H && gx >= 0 && gx < IMG_W) {
            size_t o = pbase + (size_t)gy * IMG_W + gx;
            xv = x[o];
            yv = y[o];
        }
        sx[r][c] = xv;
        sy[r][c] = yv;
    }
    __syncthreads();

    // ---- pass 1: horizontal blur of the 5 products ----
    for (int idx = t; idx < IN_T * TILE; idx += 256) {
        int r = idx / TILE, c = idx % TILE;
        float a0 = 0.f, a1 = 0.f, a2 = 0.f, a3 = 0.f, a4 = 0.f;
#pragma unroll
        for (int k = 0; k < 11; ++k) {
            float xv = sx[r][c + k];
            float yv = sy[r][c + k];
            float w = g[k];
            a0 += w * xv;
            a1 += w * yv;
            a2 += w * xv * xv;
            a3 += w * yv * yv;
            a4 += w * xv * yv;
        }
        hbuf[0][r][c] = a0;
        hbuf[1][r][c] = a1;
        hbuf[2][r][c] = a2;
        hbuf[3][r][c] = a3;
        hbuf[4][r][c] = a4;
    }
    __syncthreads();

    // ---- pass 2: vertical blur + ssim ----
    const float C1 = 0.0001f;   // 0.01^2
    const float C2 = 0.0009f;   // 0.03^2
    float lsum = 0.f;
    for (int idx = t; idx < TILE * TILE; idx += 256) {
        int r = idx / TILE, c = idx % TILE;
        float mu1 = 0.f, mu2 = 0.f, exx = 0.f, eyy = 0.f, exy = 0.f;
#pragma unroll
        for (int k = 0; k < 11; ++k) {
            float w = g[k];
            mu1 += w * hbuf[0][r + k][c];
            mu2 += w * hbuf[1][r + k][c];
            exx += w * hbuf[2][r + k][c];
            eyy += w * hbuf[3][r + k][c];
            exy += w * hbuf[4][r + k][c];
        }
        float m11 = mu1 * mu1, m22 = mu2 * mu2, m12 = mu1 * mu2;
        float s1 = exx - m11, s2 = eyy - m22, s12 = exy - m12;
        float num = (2.f * m12 + C1) * (2.f * s12 + C2);
        float den = (m11 + m22 + C1) * (s1 + s2 + C2);
        lsum += num / den;
    }

    // ---- block reduction ----
#pragma unroll
    for (int off = 32; off >= 1; off >>= 1)
        lsum += __shfl_down(lsum, off, 64);
    if ((t & 63) == 0) wsum[t >> 6] = lsum;
    __syncthreads();
    if (t == 0) {
        float b = wsum[0] + wsum[1] + wsum[2] + wsum[3];
        partial[(size_t)blockIdx.z * (gridDim.x * gridDim.y)
                + blockIdx.y * gridDim.x + blockIdx.x] = b;
    }
}

__global__ __launch_bounds__(256)
void dssim_final(const float* __restrict__ partial, float* __restrict__ out) {
    __shared__ float wsum[4];
    float s = 0.f;
    for (int i = threadIdx.x; i < NBLK; i += 256) s += partial[i];
#pragma unroll
    for (int off = 32; off >= 1; off >>= 1)
        s += __shfl_down(s, off, 64);
    if ((threadIdx.x & 63) == 0) wsum[threadIdx.x >> 6] = s;
    __syncthreads();
    if (threadIdx.x == 0) {
        float tot = wsum[0] + wsum[1] + wsum[2] + wsum[3];
        out[0] = 1.0f - tot / (float)NPIX;
    }
}

extern "C" void kernel_launch(void* const* d_in, const int* in_sizes, int n_in,
                              void* d_out, int out_size, void* d_ws, size_t ws_size,
                              hipStream_t stream) {
    const float* x = (const float*)d_in[0];
    const float* y = (const float*)d_in[1];
    float* out = (float*)d_out;
    float* partial = (float*)d_ws;   // needs NBLK*4 = 48 KiB of workspace

    dim3 grid(IMG_W / TILE, IMG_H / TILE, 48);   // 16 x 16 x 48 = 12288 blocks
    dim3 block(256);
    dssim_main<<<grid, block, 0, stream>>>(x, y, partial);
    dssim_final<<<1, block, 0, stream>>>(partial, out);
}

// Round 2
// 72.872 us; speedup vs baseline: 1.8352x; 1.8352x over previous
//
#include <hip/hip_runtime.h>

// DSSIM = 1 - mean(SSIM), 11x11 gaussian (sigma=1.5), zero-pad, fp32.
// Column-sliding separable conv: horizontal blur per row from LDS-staged
// x,y rows; vertical blur via 11-deep static register ring (4 channels:
// x, y, (x+y)^2, (x-y)^2). Chunks of 11 rows so ring slot == unroll index.

#define IMG_W   512
#define IMG_H   512
#define NPLANES 48

#define TW 256                 // tile width = blockDim.x (1 column/thread)
#define TH 64                  // output rows per block
#define ROWS (TH + 10)         // 74 h-rows processed
#define LW 272                 // LDS row width: TW + 16 (float4-aligned halo)
#define NCHUNK 7               // ceil(74/11)
#define GX (IMG_W / TW)        // 2
#define GY (IMG_H / TH)        // 8
#define NBLK (GX * GY * NPLANES)   // 768

__global__ __launch_bounds__(256)
void dssim_main(const float* __restrict__ xin, const float* __restrict__ yin,
                float* __restrict__ partial) {
    __shared__ float ls[2][11][LW];    // [input][row-slot][col]  23.9 KB
    __shared__ float wpart[4];

    const int t   = threadIdx.x;
    const int tx0 = blockIdx.x * TW;
    const int ty0 = blockIdx.y * TH;
    const size_t pbase = (size_t)blockIdx.z * (IMG_W * IMG_H);
    const int base4 = (tx0 >> 2) - 2;  // first staged float4 column index

    // gaussian weights (normalized) — matches reference within fp32 rounding
    float g[11];
    {
        float s = 0.f;
#pragma unroll
        for (int i = 0; i < 11; ++i) {
            float d = (float)(i - 5);
            g[i] = expf(-(d * d) * (1.0f / 4.5f));
            s += g[i];
        }
        float inv = 1.0f / s;
#pragma unroll
        for (int i = 0; i < 11; ++i) g[i] *= inv;
    }

    const float C1 = 0.0001f, C2 = 0.0009f;

    // register rings: h-blurred {x, y, (x+y)^2, (x-y)^2}, slot = row % 11
    float r0[11], r1[11], r2[11], r3[11];
    float lsum = 0.f;

    for (int c = 0; c < NCHUNK; ++c) {
        const int c0 = c * 11;

        // ---- stage 11 rows of x and y (float4, zero-padded) ----
        __syncthreads();
        for (int idx = t; idx < 2 * 11 * 68; idx += 256) {
            const int which = idx >= 748 ? 1 : 0;       // 0:x 1:y
            const int rem   = which ? idx - 748 : idx;
            const int j     = rem / 68;                 // row slot 0..10
            const int c4    = rem - j * 68;             // float4 col in tile
            const int i     = c0 + j;
            const int gr    = ty0 - 5 + i;
            const int gc4   = base4 + c4;
            float4 v = make_float4(0.f, 0.f, 0.f, 0.f);
            if (i < ROWS && gr >= 0 && gr < IMG_H && gc4 >= 0 && gc4 < (IMG_W / 4)) {
                const float* src = which ? yin : xin;
                v = *(const float4*)(src + pbase + (size_t)gr * IMG_W + (gc4 << 2));
            }
            *(float4*)&ls[which][j][c4 << 2] = v;
        }
        __syncthreads();

        // ---- compute: h-blur each row into ring; emit outputs once warm ----
#pragma unroll
        for (int j = 0; j < 11; ++j) {
            const int i = c0 + j;                 // i % 11 == j  (c0 = 11c)
            if (i < ROWS) {
                float a0 = 0.f, a1 = 0.f, a2 = 0.f, a3 = 0.f;
#pragma unroll
                for (int k = 0; k < 11; ++k) {
                    const float xv = ls[0][j][t + 3 + k];
                    const float yv = ls[1][j][t + 3 + k];
                    const float u = xv + yv;
                    const float w = xv - yv;
                    const float gk = g[k];
                    a0 = fmaf(gk, xv, a0);
                    a1 = fmaf(gk, yv, a1);
                    a2 = fmaf(gk * u, u, a2);
                    a3 = fmaf(gk * w, w, a3);
                }
                r0[j] = a0; r1[j] = a1; r2[j] = a2; r3[j] = a3;

                if (i >= 10) {                    // output row (i-10) of tile
                    float mu1 = 0.f, mu2 = 0.f, Pp = 0.f, Mm = 0.f;
#pragma unroll
                    for (int k = 0; k < 11; ++k) {
                        const int s = (j + 1 + k) % 11;   // oldest-first
                        const float gk = g[k];
                        mu1 = fmaf(gk, r0[s], mu1);
                        mu2 = fmaf(gk, r1[s], mu2);
                        Pp  = fmaf(gk, r2[s], Pp);
                        Mm  = fmaf(gk, r3[s], Mm);
                    }
                    const float m11 = mu1 * mu1;
                    const float m22 = mu2 * mu2;
                    const float m12 = mu1 * mu2;
                    // s1+s2 = 0.5(P+M) - m11 - m22 ; 2*s12 = 0.5(P-M) - 2*m12
                    const float sApC2 = fmaf(0.5f, Pp + Mm, -(m11 + m22)) + C2;
                    const float s12x2 = fmaf(0.5f, Pp - Mm, -2.f * m12);
                    const float num = fmaf(2.f, m12, C1) * (s12x2 + C2);
                    const float den = (m11 + m22 + C1) * sApC2;
                    lsum += num * __builtin_amdgcn_rcpf(den);
                }
            }
        }
    }

    // ---- block reduction ----
#pragma unroll
    for (int off = 32; off >= 1; off >>= 1)
        lsum += __shfl_down(lsum, off, 64);
    if ((t & 63) == 0) wpart[t >> 6] = lsum;
    __syncthreads();
    if (t == 0) {
        partial[((size_t)blockIdx.z * GY + blockIdx.y) * GX + blockIdx.x] =
            wpart[0] + wpart[1] + wpart[2] + wpart[3];
    }
}

__global__ __launch_bounds__(256)
void dssim_final(const float* __restrict__ partial, float* __restrict__ out) {
    __shared__ double wsum[4];
    double s = 0.0;
    for (int i = threadIdx.x; i < NBLK; i += 256) s += (double)partial[i];
#pragma unroll
    for (int off = 32; off >= 1; off >>= 1)
        s += __shfl_down(s, off, 64);
    if ((threadIdx.x & 63) == 0) wsum[threadIdx.x >> 6] = s;
    __syncthreads();
    if (threadIdx.x == 0) {
        const double tot = wsum[0] + wsum[1] + wsum[2] + wsum[3];
        out[0] = (float)(1.0 - tot / 12582912.0);
    }
}

extern "C" void kernel_launch(void* const* d_in, const int* in_sizes, int n_in,
                              void* d_out, int out_size, void* d_ws, size_t ws_size,
                              hipStream_t stream) {
    const float* x = (const float*)d_in[0];
    const float* y = (const float*)d_in[1];
    float* out = (float*)d_out;
    float* partial = (float*)d_ws;   // NBLK*4 = 3 KiB

    dim3 grid(GX, GY, NPLANES);      // 2 x 8 x 48 = 768 blocks
    dim3 block(256);
    dssim_main<<<grid, block, 0, stream>>>(x, y, partial);
    dssim_final<<<1, block, 0, stream>>>(partial, out);
}

// Round 3
// 60.938 us; speedup vs baseline: 2.1946x; 1.1958x over previous
//
#include <hip/hip_runtime.h>

// DSSIM = 1 - mean(SSIM), 11x11 gaussian (sigma=1.5), zero-pad, fp32.
// Column-sliding separable conv. Staging computes u=x+y, w=x-y once per px;
// h-blur of {u, w, u^2, w^2} (6 VALU/tap); vertical blur via 11-deep static
// register ring; SSIM recovered from U,W,P,Q in the epilogue:
//   mu1+mu2=U, mu1-mu2=W, Exx+Eyy=(P+Q)/2, Exy=(P-Q)/4.

#define IMG_W   512
#define IMG_H   512
#define NPLANES 48

#define TW 256                 // tile width = blockDim.x (1 column/thread)
#define TH 32                  // output rows per block
#define ROWSV (TH + 10)        // 42 h-rows processed
#define LW 272                 // LDS row width: TW + 16 (float4-aligned halo)
#define NCHUNK 4               // ceil(42/11)
#define GX (IMG_W / TW)        // 2
#define GY (IMG_H / TH)        // 16
#define NBLK (GX * GY * NPLANES)   // 1536

__global__ __launch_bounds__(256, 5)
void dssim_main(const float* __restrict__ xin, const float* __restrict__ yin,
                float* __restrict__ partial) {
    __shared__ float lsU[11][LW];      // u = x+y      11.9 KB
    __shared__ float lsW[11][LW];      // w = x-y      11.9 KB
    __shared__ float wpart[4];

    const int t   = threadIdx.x;
    const int tx0 = blockIdx.x * TW;
    const int ty0 = blockIdx.y * TH;
    const size_t pbase = (size_t)blockIdx.z * (IMG_W * IMG_H);
    const int base4 = (tx0 >> 2) - 2;  // first staged float4 column index
    const float* __restrict__ xp = xin + pbase;
    const float* __restrict__ yp = yin + pbase;

    // gaussian weights (normalized) — matches reference within fp32 rounding
    float g[11];
    {
        float s = 0.f;
#pragma unroll
        for (int i = 0; i < 11; ++i) {
            float d = (float)(i - 5);
            g[i] = expf(-(d * d) * (1.0f / 4.5f));
            s += g[i];
        }
        float inv = 1.0f / s;
#pragma unroll
        for (int i = 0; i < 11; ++i) g[i] *= inv;
    }

    const float C1 = 0.0001f, C2 = 0.0009f;

    // register rings of h-blurred {u, w, u^2, w^2}, slot = row % 11
    float rU[11], rW[11], rP[11], rQ[11];
    float lsum = 0.f;

    for (int c = 0; c < NCHUNK; ++c) {
        const int c0 = c * 11;

        // ---- stage 11 rows: load x,y; store u=x+y, w=x-y (float4) ----
        __syncthreads();
        for (int idx = t; idx < 11 * 68; idx += 256) {
            const int j   = idx / 68;               // row slot 0..10
            const int c4  = idx - j * 68;           // float4 col in tile
            const int i   = c0 + j;
            const int gr  = ty0 - 5 + i;
            const int gc4 = base4 + c4;
            float4 xv = make_float4(0.f, 0.f, 0.f, 0.f);
            float4 yv = make_float4(0.f, 0.f, 0.f, 0.f);
            if (i < ROWSV && gr >= 0 && gr < IMG_H && gc4 >= 0 && gc4 < (IMG_W / 4)) {
                const size_t o = (size_t)gr * IMG_W + (gc4 << 2);
                xv = *(const float4*)(xp + o);
                yv = *(const float4*)(yp + o);
            }
            float4 u, w;
            u.x = xv.x + yv.x; u.y = xv.y + yv.y; u.z = xv.z + yv.z; u.w = xv.w + yv.w;
            w.x = xv.x - yv.x; w.y = xv.y - yv.y; w.z = xv.z - yv.z; w.w = xv.w - yv.w;
            *(float4*)&lsU[j][c4 << 2] = u;
            *(float4*)&lsW[j][c4 << 2] = w;
        }
        __syncthreads();

        // ---- h-blur each row into ring; v-blur + ssim once ring is warm ----
#pragma unroll
        for (int j = 0; j < 11; ++j) {
            const int i = c0 + j;                 // i % 11 == j
            if (i < ROWSV) {
                float au = 0.f, aw = 0.f, pu = 0.f, pw = 0.f;
#pragma unroll
                for (int k = 0; k < 11; ++k) {
                    const float vu = lsU[j][t + 3 + k];
                    const float vw = lsW[j][t + 3 + k];
                    const float gk = g[k];
                    au = fmaf(gk, vu, au);
                    aw = fmaf(gk, vw, aw);
                    const float gku = gk * vu;
                    const float gkw = gk * vw;
                    pu = fmaf(gku, vu, pu);
                    pw = fmaf(gkw, vw, pw);
                }
                rU[j] = au; rW[j] = aw; rP[j] = pu; rQ[j] = pw;

                if (i >= 10) {                    // output row (i-10)
                    float U = 0.f, W = 0.f, P = 0.f, Q = 0.f;
#pragma unroll
                    for (int k = 0; k < 11; ++k) {
                        const int s = (j + 1 + k) % 11;   // oldest-first
                        const float gk = g[k];
                        U = fmaf(gk, rU[s], U);
                        W = fmaf(gk, rW[s], W);
                        P = fmaf(gk, rP[s], P);
                        Q = fmaf(gk, rQ[s], Q);
                    }
                    // U=mu1+mu2, W=mu1-mu2, (P+Q)/2=Exx+Eyy, (P-Q)/4=Exy
                    const float U2 = U * U;
                    const float W2 = W * W;
                    const float A  = 0.5f * (U2 + W2);    // m11+m22
                    const float B  = 0.5f * (U2 - W2);    // 2*m12
                    const float num1 = B + C1;
                    const float den1 = A + C1;
                    const float den2 = fmaf(0.5f, P + Q, -A) + C2;  // s1+s2+C2
                    const float num2 = fmaf(0.5f, P - Q, -B) + C2;  // 2*s12+C2
                    lsum += num1 * num2 * __builtin_amdgcn_rcpf(den1 * den2);
                }
            }
        }
    }

    // ---- block reduction ----
#pragma unroll
    for (int off = 32; off >= 1; off >>= 1)
        lsum += __shfl_down(lsum, off, 64);
    if ((t & 63) == 0) wpart[t >> 6] = lsum;
    __syncthreads();
    if (t == 0) {
        partial[((size_t)blockIdx.z * GY + blockIdx.y) * GX + blockIdx.x] =
            wpart[0] + wpart[1] + wpart[2] + wpart[3];
    }
}

__global__ __launch_bounds__(256)
void dssim_final(const float* __restrict__ partial, float* __restrict__ out) {
    __shared__ double wsum[4];
    double s = 0.0;
    for (int i = threadIdx.x; i < NBLK; i += 256) s += (double)partial[i];
#pragma unroll
    for (int off = 32; off >= 1; off >>= 1)
        s += __shfl_down(s, off, 64);
    if ((threadIdx.x & 63) == 0) wsum[threadIdx.x >> 6] = s;
    __syncthreads();
    if (threadIdx.x == 0) {
        const double tot = wsum[0] + wsum[1] + wsum[2] + wsum[3];
        out[0] = (float)(1.0 - tot / 12582912.0);
    }
}

extern "C" void kernel_launch(void* const* d_in, const int* in_sizes, int n_in,
                              void* d_out, int out_size, void* d_ws, size_t ws_size,
                              hipStream_t stream) {
    const float* x = (const float*)d_in[0];
    const float* y = (const float*)d_in[1];
    float* out = (float*)d_out;
    float* partial = (float*)d_ws;   // NBLK*4 = 6 KiB

    dim3 grid(GX, GY, NPLANES);      // 2 x 16 x 48 = 1536 blocks
    dim3 block(256);
    dssim_main<<<grid, block, 0, stream>>>(x, y, partial);
    dssim_final<<<1, block, 0, stream>>>(partial, out);
}

// Round 4
// 60.816 us; speedup vs baseline: 2.1990x; 1.0020x over previous
//
#include <hip/hip_runtime.h>

// DSSIM = 1 - mean(SSIM), 11x11 gaussian (sigma=1.5), zero-pad, fp32.
// Full-width tile (512), 2 px/thread. Stage u=x+y, w=x-y; h-blur of
// {u,w,u^2,w^2} with 7 aligned ds_read_b64 per channel covering both
// columns' 12-slot window; shared squares. Vertical blur via 11-deep
// static register rings (slot == unroll index). SSIM from U,W,P,Q.

#define IMG_W   512
#define IMG_H   512
#define NPLANES 48
#define TH      32
#define ROWSV   (TH + 10)      // 42
#define LW      544            // 16 pad | 512 | 16 pad
#define NCHUNK  4
#define GY      (IMG_H / TH)   // 16
#define NBLK    (GY * NPLANES) // 768

__global__ __launch_bounds__(256, 3)
void dssim_main(const float* __restrict__ xin, const float* __restrict__ yin,
                float* __restrict__ partial) {
    __shared__ float lsU[11][LW];      // u = x+y   23.9 KB
    __shared__ float lsW[11][LW];      // w = x-y   23.9 KB
    __shared__ float wpart[4];

    const int t   = threadIdx.x;
    const int ty0 = blockIdx.x * TH;
    const size_t pbase = (size_t)blockIdx.y * (IMG_W * IMG_H);
    const float* __restrict__ xp = xin + pbase;
    const float* __restrict__ yp = yin + pbase;

    float g[11];
    {
        float s = 0.f;
#pragma unroll
        for (int i = 0; i < 11; ++i) {
            float d = (float)(i - 5);
            g[i] = expf(-(d * d) * (1.0f / 4.5f));
            s += g[i];
        }
        float inv = 1.0f / s;
#pragma unroll
        for (int i = 0; i < 11; ++i) g[i] *= inv;
    }

    const float C1 = 0.0001f, C2 = 0.0009f;

    // vertical rings, 2 columns per thread (cols 2t, 2t+1), slot = row%11
    float rU0[11], rU1[11], rW0[11], rW1[11];
    float rP0[11], rP1[11], rQ0[11], rQ1[11];
    float lsum = 0.f;

    for (int c = 0; c < NCHUNK; ++c) {
        const int c0 = c * 11;

        // ---- stage 11 rows: u=x+y, w=x-y, float4, 16-col zero pads ----
        __syncthreads();
        for (int idx = t; idx < 11 * 136; idx += 256) {
            const int j = idx / 136;          // row slot
            const int s = idx - j * 136;      // float4 slot in padded row
            const int i = c0 + j;
            const int gr = ty0 - 5 + i;
            float4 xv = make_float4(0.f, 0.f, 0.f, 0.f);
            float4 yv = make_float4(0.f, 0.f, 0.f, 0.f);
            if (i < ROWSV && gr >= 0 && gr < IMG_H && s >= 4 && s <= 131) {
                const size_t o = (size_t)gr * IMG_W + ((s - 4) << 2);
                xv = *(const float4*)(xp + o);
                yv = *(const float4*)(yp + o);
            }
            float4 u, w;
            u.x = xv.x + yv.x; u.y = xv.y + yv.y; u.z = xv.z + yv.z; u.w = xv.w + yv.w;
            w.x = xv.x - yv.x; w.y = xv.y - yv.y; w.z = xv.z - yv.z; w.w = xv.w - yv.w;
            *(float4*)&lsU[j][s << 2] = u;
            *(float4*)&lsW[j][s << 2] = w;
        }
        __syncthreads();

        // ---- h-blur each row into rings; v-blur + ssim once warm ----
#pragma unroll
        for (int j = 0; j < 11; ++j) {
            const int i = c0 + j;                    // i % 11 == j
            if (i < ROWSV) {
                // aligned b64 window: LDS idx [2t+10, 2t+23]; cols 2t,2t+1
                // col c maps to idx c+16; windows use idx [2t+11, 2t+22]
                float vU[14], vW[14];
                const int b = 2 * t + 10;
#pragma unroll
                for (int m = 0; m < 7; ++m) {
                    *(float2*)&vU[2 * m] = *(const float2*)&lsU[j][b + 2 * m];
                    *(float2*)&vW[2 * m] = *(const float2*)&lsW[j][b + 2 * m];
                }
                float au0 = 0.f, au1 = 0.f, aw0 = 0.f, aw1 = 0.f;
                float pu0 = 0.f, pu1 = 0.f, pw0 = 0.f, pw1 = 0.f;
#pragma unroll
                for (int k = 0; k < 11; ++k) {
                    const float gk = g[k];
                    au0 = fmaf(gk, vU[1 + k], au0);
                    au1 = fmaf(gk, vU[2 + k], au1);
                    aw0 = fmaf(gk, vW[1 + k], aw0);
                    aw1 = fmaf(gk, vW[2 + k], aw1);
                }
#pragma unroll
                for (int q = 1; q <= 12; ++q) {      // shared squares
                    const float su = vU[q] * vU[q];
                    const float sw = vW[q] * vW[q];
                    if (q <= 11) { pu0 = fmaf(g[q - 1], su, pu0);
                                   pw0 = fmaf(g[q - 1], sw, pw0); }
                    if (q >= 2)  { pu1 = fmaf(g[q - 2], su, pu1);
                                   pw1 = fmaf(g[q - 2], sw, pw1); }
                }
                rU0[j] = au0; rU1[j] = au1; rW0[j] = aw0; rW1[j] = aw1;
                rP0[j] = pu0; rP1[j] = pu1; rQ0[j] = pw0; rQ1[j] = pw1;

                if (i >= 10) {                       // output row i-10
                    float U0 = 0.f, U1 = 0.f, W0 = 0.f, W1 = 0.f;
                    float P0 = 0.f, P1 = 0.f, Q0 = 0.f, Q1 = 0.f;
#pragma unroll
                    for (int k = 0; k < 11; ++k) {
                        const int s = (j + 1 + k) % 11;   // oldest-first
                        const float gk = g[k];
                        U0 = fmaf(gk, rU0[s], U0); U1 = fmaf(gk, rU1[s], U1);
                        W0 = fmaf(gk, rW0[s], W0); W1 = fmaf(gk, rW1[s], W1);
                        P0 = fmaf(gk, rP0[s], P0); P1 = fmaf(gk, rP1[s], P1);
                        Q0 = fmaf(gk, rQ0[s], Q0); Q1 = fmaf(gk, rQ1[s], Q1);
                    }
                    // U=mu1+mu2, W=mu1-mu2, (P+Q)/2=Exx+Eyy, (P-Q)/4=Exy
                    {
                        const float U2 = U0 * U0, W2 = W0 * W0;
                        const float A = 0.5f * (U2 + W2);
                        const float B = 0.5f * (U2 - W2);
                        const float d2 = fmaf(0.5f, P0 + Q0, -A) + C2;
                        const float n2 = fmaf(0.5f, P0 - Q0, -B) + C2;
                        lsum += (B + C1) * n2 *
                                __builtin_amdgcn_rcpf((A + C1) * d2);
                    }
                    {
                        const float U2 = U1 * U1, W2 = W1 * W1;
                        const float A = 0.5f * (U2 + W2);
                        const float B = 0.5f * (U2 - W2);
                        const float d2 = fmaf(0.5f, P1 + Q1, -A) + C2;
                        const float n2 = fmaf(0.5f, P1 - Q1, -B) + C2;
                        lsum += (B + C1) * n2 *
                                __builtin_amdgcn_rcpf((A + C1) * d2);
                    }
                }
            }
        }
    }

    // ---- block reduction ----
#pragma unroll
    for (int off = 32; off >= 1; off >>= 1)
        lsum += __shfl_down(lsum, off, 64);
    if ((t & 63) == 0) wpart[t >> 6] = lsum;
    __syncthreads();
    if (t == 0) {
        partial[(size_t)blockIdx.y * GY + blockIdx.x] =
            wpart[0] + wpart[1] + wpart[2] + wpart[3];
    }
}

__global__ __launch_bounds__(256)
void dssim_final(const float* __restrict__ partial, float* __restrict__ out) {
    __shared__ double wsum[4];
    double s = 0.0;
    for (int i = threadIdx.x; i < NBLK; i += 256) s += (double)partial[i];
#pragma unroll
    for (int off = 32; off >= 1; off >>= 1)
        s += __shfl_down(s, off, 64);
    if ((threadIdx.x & 63) == 0) wsum[threadIdx.x >> 6] = s;
    __syncthreads();
    if (threadIdx.x == 0) {
        const double tot = wsum[0] + wsum[1] + wsum[2] + wsum[3];
        out[0] = (float)(1.0 - tot / 12582912.0);
    }
}

extern "C" void kernel_launch(void* const* d_in, const int* in_sizes, int n_in,
                              void* d_out, int out_size, void* d_ws, size_t ws_size,
                              hipStream_t stream) {
    const float* x = (const float*)d_in[0];
    const float* y = (const float*)d_in[1];
    float* out = (float*)d_out;
    float* partial = (float*)d_ws;   // NBLK*4 = 3 KiB

    dim3 grid(GY, NPLANES);          // 16 x 48 = 768 blocks
    dim3 block(256);
    dssim_main<<<grid, block, 0, stream>>>(x, y, partial);
    dssim_final<<<1, block, 0, stream>>>(partial, out);
}